// Round 1
// baseline (1313.298 us; speedup 1.0000x reference)
//
#include <hip/hip_runtime.h>
#include <hip/hip_bf16.h>

// ---------------------------------------------------------------------------
// Layer 1/2: C = relu(A @ B + bias), A [M,K] row-major, B [K,N] row-major.
// 128x128 block tile, BK=16, 256 threads, 8x8 microtile per thread, fp32.
// ---------------------------------------------------------------------------
#define BM 128
#define BN 128
#define BK 16
#define TM 8
#define TN 8

__global__ __launch_bounds__(256) void gemm_bias_relu(
    const float* __restrict__ A, const float* __restrict__ B,
    const float* __restrict__ bias, float* __restrict__ C,
    int M, int N, int K)
{
    // As padded to stride 132 (132*4B = 528B, 16B aligned) to break 4-way
    // bank conflicts on the transposed staging stores.
    __shared__ float As[BK][BM + 4];
    __shared__ float Bs[BK][BN];

    const int bn = blockIdx.x;   // N tile
    const int bm = blockIdx.y;   // M tile
    const int tid = threadIdx.x;
    const int tx = tid & 15;     // 16 thread-cols * TN=8 -> 128
    const int ty = tid >> 4;     // 16 thread-rows * TM=8 -> 128

    const float* Ablk = A + (size_t)bm * BM * K;
    const float* Bblk = B + (size_t)bn * BN;

    float acc[TM][TN];
    #pragma unroll
    for (int i = 0; i < TM; ++i)
        #pragma unroll
        for (int j = 0; j < TN; ++j) acc[i][j] = 0.0f;

    for (int k0 = 0; k0 < K; k0 += BK) {
        // Stage A tile (128 x 16) transposed into As[k][m]; 512 float4 loads.
        // Stage B tile (16 x 128) into Bs[k][n]; 512 float4 loads.
        #pragma unroll
        for (int l = 0; l < 2; ++l) {
            int f = tid + l * 256;
            int arow = f >> 2;          // 0..127
            int ac4  = f & 3;           // 0..3 -> k offset ac4*4
            float4 va = *(const float4*)(Ablk + (size_t)arow * K + k0 + ac4 * 4);
            As[ac4 * 4 + 0][arow] = va.x;
            As[ac4 * 4 + 1][arow] = va.y;
            As[ac4 * 4 + 2][arow] = va.z;
            As[ac4 * 4 + 3][arow] = va.w;

            int bkr = f >> 5;           // 0..15
            int bn4 = f & 31;           // 0..31
            *(float4*)&Bs[bkr][bn4 * 4] =
                *(const float4*)(Bblk + (size_t)(k0 + bkr) * N + bn4 * 4);
        }
        __syncthreads();

        #pragma unroll
        for (int k = 0; k < BK; ++k) {
            float a[TM], b[TN];
            *(float4*)&a[0] = *(float4*)&As[k][ty * TM];
            *(float4*)&a[4] = *(float4*)&As[k][ty * TM + 4];
            *(float4*)&b[0] = *(float4*)&Bs[k][tx * TN];
            *(float4*)&b[4] = *(float4*)&Bs[k][tx * TN + 4];
            #pragma unroll
            for (int i = 0; i < TM; ++i)
                #pragma unroll
                for (int j = 0; j < TN; ++j)
                    acc[i][j] += a[i] * b[j];
        }
        __syncthreads();
    }

    // Epilogue: bias + relu, coalesced float4 stores.
    float bv[TN];
    *(float4*)&bv[0] = *(const float4*)(bias + (size_t)bn * BN + tx * TN);
    *(float4*)&bv[4] = *(const float4*)(bias + (size_t)bn * BN + tx * TN + 4);
    #pragma unroll
    for (int i = 0; i < TM; ++i) {
        float o[TN];
        #pragma unroll
        for (int j = 0; j < TN; ++j)
            o[j] = fmaxf(acc[i][j] + bv[j], 0.0f);
        size_t r = (size_t)(bm * BM + ty * TM + i) * N + bn * BN + tx * TN;
        *(float4*)(C + r)     = *(float4*)&o[0];
        *(float4*)(C + r + 4) = *(float4*)&o[4];
    }
}

// ---------------------------------------------------------------------------
// Layer 3: scores[r] = dot(H[r,:], W3) + b3.  One wave per row.
// Also writes scores into the second half of d_out (output 1).
// ---------------------------------------------------------------------------
__global__ __launch_bounds__(256) void matvec_bias(
    const float* __restrict__ H, const float* __restrict__ W,
    const float* __restrict__ b3, float* __restrict__ scores,
    float* __restrict__ out_scores, int N)
{
    const int wave = threadIdx.x >> 6;
    const int lane = threadIdx.x & 63;
    const int row  = blockIdx.x * 4 + wave;
    const float* h = H + (size_t)row * N;

    float s = 0.0f;
    // N=2048: 8 strided float4 loads per lane (contiguous 1KB per wave-load).
    for (int w = 0; w < N / 256; ++w) {
        float4 v = *(const float4*)(h + w * 256 + lane * 4);
        float4 g = *(const float4*)(W + w * 256 + lane * 4);
        s += v.x * g.x + v.y * g.y + v.z * g.z + v.w * g.w;
    }
    #pragma unroll
    for (int off = 32; off > 0; off >>= 1) s += __shfl_down(s, off);
    if (lane == 0) {
        float r = s + b3[0];
        scores[row] = r;
        out_scores[row] = r;
    }
}

// ---------------------------------------------------------------------------
// soft_rank over n=4096 scores, single block of 1024 threads.
//   1) u64-key bitonic sort in LDS: key = (desc_float_map(z) << 32) | index
//      -> ascending u64 sort == stable descending argsort of z.
//   2) PAV isotonic non-increasing fit of y_i = s_i - (n-i), thread 0,
//      stack top cached in registers (typical case: register-only loop).
//   3) block means -> per-element dual via parallel binary search,
//      primal = s - dual, scatter rank[perm[i]] = primal_i.
// LDS plan (64 KB total, regions reused across phases):
//   [0,32760)   keys (sort)  ->  bsum f64 stack  ->  bmean f32
//   [32760)     nb (int)
//   [32768,49152) svals f32[4096]
//   [49152,57344) perm  u16[4096]
//   [57344,65536) bstart u16[4096]
// ---------------------------------------------------------------------------
__global__ __launch_bounds__(1024) void soft_rank_kernel(
    const float* __restrict__ scores, float* __restrict__ rank_out)
{
    constexpr int n = 4096;
    __shared__ __align__(16) unsigned char lds[65536];
    unsigned long long* keys = (unsigned long long*)lds;
    double* bsum  = (double*)lds;
    float*  bmean = (float*)lds;
    int*    nb_p  = (int*)(lds + 32760);
    float*  svals = (float*)(lds + 32768);
    unsigned short* perm   = (unsigned short*)(lds + 49152);
    unsigned short* bstart = (unsigned short*)(lds + 57344);

    const int tid = threadIdx.x;

    // ---- build keys ----
    for (int t = tid; t < n; t += 1024) {
        unsigned ub = __float_as_uint(scores[t]);
        unsigned m  = (ub & 0x80000000u) ? ~ub : (ub | 0x80000000u); // asc map
        unsigned d  = ~m;                                            // desc map
        keys[t] = ((unsigned long long)d << 32) | (unsigned)t;
    }
    __syncthreads();

    // ---- bitonic sort (ascending u64) ----
    for (int k = 2; k <= n; k <<= 1) {
        for (int j = k >> 1; j > 0; j >>= 1) {
            for (int t = tid; t < n; t += 1024) {
                int l = t ^ j;
                if (l > t) {
                    unsigned long long a = keys[t], b = keys[l];
                    bool up = ((t & k) == 0);
                    bool sw = up ? (a > b) : (a < b);
                    if (sw) { keys[t] = b; keys[l] = a; }
                }
            }
            __syncthreads();
        }
    }

    // ---- extract sorted values + permutation ----
    for (int t = tid; t < n; t += 1024) {
        unsigned long long key = keys[t];
        unsigned d = (unsigned)(key >> 32);
        unsigned m = ~d;
        unsigned ub = (m & 0x80000000u) ? (m ^ 0x80000000u) : ~m;
        svals[t] = __uint_as_float(ub);
        perm[t]  = (unsigned short)(key & 0xFFFFu);
    }
    __syncthreads();

    // ---- PAV (thread 0), stack top in registers ----
    if (tid == 0) {
        int depth = 0;       // total blocks including register top
        double tsum = 0.0;
        int tstart = 0;
        for (int i = 0; i < n; ++i) {
            double csum = (double)svals[i] - (double)(n - i);  // y_i
            int cstart = i;
            while (depth > 0) {
                // top block [tstart,cstart), cur [cstart,i+1)
                double tnum = tsum * (double)(i + 1 - cstart);
                double cnum = csum * (double)(cstart - tstart);
                if (tnum <= cnum) {   // mean(top) <= mean(cur) -> merge
                    csum += tsum;
                    cstart = tstart;
                    depth--;
                    if (depth > 0) { tsum = bsum[depth - 1]; tstart = bstart[depth - 1]; }
                } else break;
            }
            if (depth > 0) { bsum[depth - 1] = tsum; bstart[depth - 1] = tstart; }
            tsum = csum; tstart = cstart; depth++;
        }
        // finalize: blocks are LDS[0..depth-2] plus register top
        bstart[depth - 1] = (unsigned short)tstart;
        int nb = depth;
        for (int b = 0; b < nb; ++b) {
            int s = bstart[b];
            int e = (b + 1 < nb) ? (int)bstart[b + 1] : n;
            double sum = (b == nb - 1) ? tsum : bsum[b];
            bmean[b] = (float)(sum / (double)(e - s));  // 4b write <= 8b read: safe
        }
        *nb_p = nb;
    }
    __syncthreads();

    // ---- dual lookup (binary search over block starts) + scatter ----
    const int nb = *nb_p;
    for (int t = tid; t < n; t += 1024) {
        int lo = 0, hi = nb - 1;
        while (lo < hi) {
            int mid = (lo + hi + 1) >> 1;
            if ((int)bstart[mid] <= t) lo = mid; else hi = mid - 1;
        }
        float primal = svals[t] - bmean[lo];
        rank_out[(int)perm[t]] = primal;
    }
}

// ---------------------------------------------------------------------------
extern "C" void kernel_launch(void* const* d_in, const int* in_sizes, int n_in,
                              void* d_out, int out_size, void* d_ws, size_t ws_size,
                              hipStream_t stream) {
    const float* x  = (const float*)d_in[0];
    const float* W1 = (const float*)d_in[1];
    const float* b1 = (const float*)d_in[2];
    const float* W2 = (const float*)d_in[3];
    const float* b2 = (const float*)d_in[4];
    const float* W3 = (const float*)d_in[5];
    const float* b3 = (const float*)d_in[6];
    float* out = (float*)d_out;   // [0,4096): rank, [4096,8192): scores

    const int B = 4096, D_IN = 512, H = 2048;

    float* h1 = (float*)d_ws;                       // 4096*2048 fp32 = 32 MB
    float* h2 = h1 + (size_t)B * H;                 // 32 MB
    float* sc = h2 + (size_t)B * H;                 // 16 KB

    dim3 grid(H / BN, B / BM);   // (16, 32)
    gemm_bias_relu<<<grid, 256, 0, stream>>>(x,  W1, b1, h1, B, H, D_IN);
    gemm_bias_relu<<<grid, 256, 0, stream>>>(h1, W2, b2, h2, B, H, H);
    matvec_bias<<<B / 4, 256, 0, stream>>>(h2, W3, b3, sc, out + B, H);
    soft_rank_kernel<<<1, 1024, 0, stream>>>(sc, out);
}

// Round 2
// 692.932 us; speedup vs baseline: 1.8953x; 1.8953x over previous
//
#include <hip/hip_runtime.h>
#include <hip/hip_bf16.h>

// ---------------------------------------------------------------------------
// Layer 1/2: C = relu(A @ B + bias), A [M,K] row-major, B [K,N] row-major.
// 128x128 block tile, BK=16, 256 threads, 8x8 microtile per thread, fp32.
// ---------------------------------------------------------------------------
#define BM 128
#define BN 128
#define BK 16
#define TM 8
#define TN 8

__global__ __launch_bounds__(256) void gemm_bias_relu(
    const float* __restrict__ A, const float* __restrict__ B,
    const float* __restrict__ bias, float* __restrict__ C,
    int M, int N, int K)
{
    __shared__ float As[BK][BM + 4];
    __shared__ float Bs[BK][BN];

    const int bn = blockIdx.x;   // N tile
    const int bm = blockIdx.y;   // M tile
    const int tid = threadIdx.x;
    const int tx = tid & 15;     // 16 thread-cols * TN=8 -> 128
    const int ty = tid >> 4;     // 16 thread-rows * TM=8 -> 128

    const float* Ablk = A + (size_t)bm * BM * K;
    const float* Bblk = B + (size_t)bn * BN;

    float acc[TM][TN];
    #pragma unroll
    for (int i = 0; i < TM; ++i)
        #pragma unroll
        for (int j = 0; j < TN; ++j) acc[i][j] = 0.0f;

    for (int k0 = 0; k0 < K; k0 += BK) {
        #pragma unroll
        for (int l = 0; l < 2; ++l) {
            int f = tid + l * 256;
            int arow = f >> 2;          // 0..127
            int ac4  = f & 3;           // 0..3 -> k offset ac4*4
            float4 va = *(const float4*)(Ablk + (size_t)arow * K + k0 + ac4 * 4);
            As[ac4 * 4 + 0][arow] = va.x;
            As[ac4 * 4 + 1][arow] = va.y;
            As[ac4 * 4 + 2][arow] = va.z;
            As[ac4 * 4 + 3][arow] = va.w;

            int bkr = f >> 5;           // 0..15
            int bn4 = f & 31;           // 0..31
            *(float4*)&Bs[bkr][bn4 * 4] =
                *(const float4*)(Bblk + (size_t)(k0 + bkr) * N + bn4 * 4);
        }
        __syncthreads();

        #pragma unroll
        for (int k = 0; k < BK; ++k) {
            float a[TM], b[TN];
            *(float4*)&a[0] = *(float4*)&As[k][ty * TM];
            *(float4*)&a[4] = *(float4*)&As[k][ty * TM + 4];
            *(float4*)&b[0] = *(float4*)&Bs[k][tx * TN];
            *(float4*)&b[4] = *(float4*)&Bs[k][tx * TN + 4];
            #pragma unroll
            for (int i = 0; i < TM; ++i)
                #pragma unroll
                for (int j = 0; j < TN; ++j)
                    acc[i][j] += a[i] * b[j];
        }
        __syncthreads();
    }

    float bv[TN];
    *(float4*)&bv[0] = *(const float4*)(bias + (size_t)bn * BN + tx * TN);
    *(float4*)&bv[4] = *(const float4*)(bias + (size_t)bn * BN + tx * TN + 4);
    #pragma unroll
    for (int i = 0; i < TM; ++i) {
        float o[TN];
        #pragma unroll
        for (int j = 0; j < TN; ++j)
            o[j] = fmaxf(acc[i][j] + bv[j], 0.0f);
        size_t r = (size_t)(bm * BM + ty * TM + i) * N + bn * BN + tx * TN;
        *(float4*)(C + r)     = *(float4*)&o[0];
        *(float4*)(C + r + 4) = *(float4*)&o[4];
    }
}

// ---------------------------------------------------------------------------
// Layer 3: scores[r] = dot(H[r,:], W3) + b3.  One wave per row.
// ---------------------------------------------------------------------------
__global__ __launch_bounds__(256) void matvec_bias(
    const float* __restrict__ H, const float* __restrict__ W,
    const float* __restrict__ b3, float* __restrict__ scores,
    float* __restrict__ out_scores, int N)
{
    const int wave = threadIdx.x >> 6;
    const int lane = threadIdx.x & 63;
    const int row  = blockIdx.x * 4 + wave;
    const float* h = H + (size_t)row * N;

    float s = 0.0f;
    for (int w = 0; w < N / 256; ++w) {
        float4 v = *(const float4*)(h + w * 256 + lane * 4);
        float4 g = *(const float4*)(W + w * 256 + lane * 4);
        s += v.x * g.x + v.y * g.y + v.z * g.z + v.w * g.w;
    }
    #pragma unroll
    for (int off = 32; off > 0; off >>= 1) s += __shfl_down(s, off);
    if (lane == 0) {
        float r = s + b3[0];
        scores[row] = r;
        out_scores[row] = r;
    }
}

// ---------------------------------------------------------------------------
// soft_rank over n=4096 scores, single block of 1024 threads.
//   1) u64-key bitonic sort (stable descending argsort).
//   2) CHUNKED PAV: 64 chunks x 64 elems; serial PAV per chunk on 64 parallel
//      threads (weighted-block lists with decreasing means), then a short
//      thread-0 merge over block lists (PAV is associative over pooled
//      blocks). Expected total blocks ~64 since y = s - [n..1] is almost
//      everywhere increasing; worst case (4096 blocks) still correct via
//      in-place stack compaction (global write idx <= chunk read idx).
//   3) per-element dual via binary search over block starts; primal = s-dual;
//      scatter rank[perm[i]].
// LDS (exactly 64 KB, regions reused):
//   [0,32768)     keys u64[4096] (sort)  ->  bsum f64[4096] (chunk+global)
//   [32768,49152) svals f32[4096]
//   [49152,57344) perm  u16[4096]
//   [57344,65536) bstart u16[4096] (chunk stacks -> global stack; 0xFFFF sentinel)
// nb (global block count) broadcast through a ws int (LDS is full worst-case).
// ---------------------------------------------------------------------------
__global__ __launch_bounds__(1024) void soft_rank_kernel(
    const float* __restrict__ scores, float* __restrict__ rank_out, int* nb_ws)
{
    constexpr int n = 4096;
    __shared__ __align__(16) unsigned char lds[65536];
    unsigned long long* keys = (unsigned long long*)lds;
    double* bsum  = (double*)lds;
    float*  svals = (float*)(lds + 32768);
    unsigned short* perm   = (unsigned short*)(lds + 49152);
    unsigned short* bstart = (unsigned short*)(lds + 57344);

    const int tid = threadIdx.x;

    // ---- build keys ----
    for (int t = tid; t < n; t += 1024) {
        unsigned ub = __float_as_uint(scores[t]);
        unsigned m  = (ub & 0x80000000u) ? ~ub : (ub | 0x80000000u); // asc map
        unsigned d  = ~m;                                            // desc map
        keys[t] = ((unsigned long long)d << 32) | (unsigned)t;
    }
    __syncthreads();

    // ---- bitonic sort (ascending u64) ----
    for (int k = 2; k <= n; k <<= 1) {
        for (int j = k >> 1; j > 0; j >>= 1) {
            for (int t = tid; t < n; t += 1024) {
                int l = t ^ j;
                if (l > t) {
                    unsigned long long a = keys[t], b = keys[l];
                    bool up = ((t & k) == 0);
                    bool sw = up ? (a > b) : (a < b);
                    if (sw) { keys[t] = b; keys[l] = a; }
                }
            }
            __syncthreads();
        }
    }

    // ---- extract sorted values + permutation ----
    for (int t = tid; t < n; t += 1024) {
        unsigned long long key = keys[t];
        unsigned d = (unsigned)(key >> 32);
        unsigned m = ~d;
        unsigned ub = (m & 0x80000000u) ? (m ^ 0x80000000u) : ~m;
        svals[t] = __uint_as_float(ub);
        perm[t]  = (unsigned short)(key & 0xFFFFu);
    }
    __syncthreads();

    // ---- Phase A: per-chunk PAV, 64 threads, chunk c = tid ----
    if (tid < 64) {
        const int base = tid << 6;        // chunk covers [base, base+64)
        int depth = 0;                    // stack size incl. register top
        double rtsum = 0.0; int rtstart = 0;
        for (int s = 0; s < 64; ++s) {
            int i = base + s;
            double csum = (double)svals[i] - (double)(n - i);   // y_i
            int cs = i;
            const int ce = i + 1;
            while (depth > 0) {
                // top [rtstart, cs), current [cs, ce)
                if (rtsum * (double)(ce - cs) <= csum * (double)(cs - rtstart)) {
                    csum += rtsum; cs = rtstart; depth--;
                    if (depth > 0) {
                        rtsum = bsum[base + depth - 1];
                        rtstart = bstart[base + depth - 1];
                    }
                } else break;
            }
            if (depth > 0) {
                bsum[base + depth - 1] = rtsum;
                bstart[base + depth - 1] = (unsigned short)rtstart;
            }
            rtsum = csum; rtstart = cs; depth++;
        }
        bsum[base + depth - 1] = rtsum;
        bstart[base + depth - 1] = (unsigned short)rtstart;
        if (depth < 64) bstart[base + depth] = 0xFFFFu;   // sentinel
    }
    __syncthreads();

    // ---- Phase B: serial merge of chunk block lists (thread 0) ----
    if (tid == 0) {
        int g = 0;                        // global stack size incl. reg top
        double gtsum = 0.0; int gtstart = 0;
        for (int c = 0; c < 64; ++c) {
            const int base = c << 6;
            for (int s = 0; s < 64; ++s) {
                const int r = base + s;
                int cs = bstart[r];
                if (cs == 0xFFFF) break;
                int ce;
                if (s < 63) {
                    int nx = bstart[r + 1];
                    ce = (nx == 0xFFFF) ? base + 64 : nx;
                } else ce = base + 64;
                double csum = bsum[r];
                while (g > 0) {
                    if (gtsum * (double)(ce - cs) <= csum * (double)(cs - gtstart)) {
                        csum += gtsum; cs = gtstart; g--;
                        if (g > 0) { gtsum = bsum[g - 1]; gtstart = bstart[g - 1]; }
                    } else break;
                }
                // push (spill old top); write idx g-1 <= consumed-1 <= r: safe
                if (g > 0) {
                    bsum[g - 1] = gtsum;
                    bstart[g - 1] = (unsigned short)gtstart;
                }
                gtsum = csum; gtstart = cs; g++;
            }
        }
        bsum[g - 1] = gtsum;
        bstart[g - 1] = (unsigned short)gtstart;
        __hip_atomic_store(nb_ws, g, __ATOMIC_RELEASE, __HIP_MEMORY_SCOPE_AGENT);
    }
    __syncthreads();
    const int nb = __hip_atomic_load(nb_ws, __ATOMIC_ACQUIRE, __HIP_MEMORY_SCOPE_AGENT);

    // ---- dual lookup (binary search over block starts) + scatter ----
    for (int t = tid; t < n; t += 1024) {
        int lo = 0, hi = nb - 1;
        while (lo < hi) {
            int mid = (lo + hi + 1) >> 1;
            if ((int)bstart[mid] <= t) lo = mid; else hi = mid - 1;
        }
        int bs = bstart[lo];
        int be = (lo + 1 < nb) ? (int)bstart[lo + 1] : n;
        float mean = (float)(bsum[lo] / (double)(be - bs));
        rank_out[(int)perm[t]] = svals[t] - mean;
    }
}

// ---------------------------------------------------------------------------
extern "C" void kernel_launch(void* const* d_in, const int* in_sizes, int n_in,
                              void* d_out, int out_size, void* d_ws, size_t ws_size,
                              hipStream_t stream) {
    const float* x  = (const float*)d_in[0];
    const float* W1 = (const float*)d_in[1];
    const float* b1 = (const float*)d_in[2];
    const float* W2 = (const float*)d_in[3];
    const float* b2 = (const float*)d_in[4];
    const float* W3 = (const float*)d_in[5];
    const float* b3 = (const float*)d_in[6];
    float* out = (float*)d_out;   // [0,4096): rank, [4096,8192): scores

    const int B = 4096, D_IN = 512, H = 2048;

    float* h1 = (float*)d_ws;                       // 32 MB
    float* h2 = h1 + (size_t)B * H;                 // 32 MB
    float* sc = h2 + (size_t)B * H;                 // 16 KB
    int*   nb = (int*)(sc + B);                     // 4 B

    dim3 grid(H / BN, B / BM);   // (16, 32)
    gemm_bias_relu<<<grid, 256, 0, stream>>>(x,  W1, b1, h1, B, H, D_IN);
    gemm_bias_relu<<<grid, 256, 0, stream>>>(h1, W2, b2, h2, B, H, H);
    matvec_bias<<<B / 4, 256, 0, stream>>>(h2, W3, b3, sc, out + B, H);
    soft_rank_kernel<<<1, 1024, 0, stream>>>(sc, out, nb);
}

// Round 3
// 266.445 us; speedup vs baseline: 4.9290x; 2.6007x over previous
//
#include <hip/hip_runtime.h>
#include <hip/hip_bf16.h>

typedef float f32x4 __attribute__((ext_vector_type(4)));
typedef __bf16 bf16x8 __attribute__((ext_vector_type(8)));

__device__ __forceinline__ unsigned short f2bf(float f) {
    unsigned u = __float_as_uint(f);
    return (unsigned short)((u + 0x7fffu + ((u >> 16) & 1u)) >> 16);  // RNE
}

// ---------------------------------------------------------------------------
// Elementwise fp32 -> bf16 (n multiple of 1024).
// ---------------------------------------------------------------------------
__global__ __launch_bounds__(256) void convert_bf16(
    const float* __restrict__ in, unsigned short* __restrict__ out)
{
    int i = (blockIdx.x * 256 + threadIdx.x) * 4;
    float4 v = *(const float4*)(in + i);
    ushort4 o = { f2bf(v.x), f2bf(v.y), f2bf(v.z), f2bf(v.w) };
    *(ushort4*)(out + i) = o;
}

// ---------------------------------------------------------------------------
// W [K,N] fp32 row-major  ->  Wt [N,K] bf16 row-major. 64x64 LDS tiles.
// ---------------------------------------------------------------------------
__global__ __launch_bounds__(256) void transpose_convert(
    const float* __restrict__ W, unsigned short* __restrict__ Wt, int K, int N)
{
    __shared__ float tile[64][65];
    const int bx = blockIdx.x;   // n tile
    const int by = blockIdx.y;   // k tile
    const int t = threadIdx.x;
    const int col4 = t & 15;     // 16 float4 per row
    const int row  = t >> 4;     // 16 rows per pass

    #pragma unroll
    for (int i = 0; i < 4; ++i) {
        int r = row + i * 16;    // k within tile
        float4 v = *(const float4*)(W + (size_t)(by * 64 + r) * N + bx * 64 + col4 * 4);
        tile[r][col4 * 4 + 0] = v.x;
        tile[r][col4 * 4 + 1] = v.y;
        tile[r][col4 * 4 + 2] = v.z;
        tile[r][col4 * 4 + 3] = v.w;
    }
    __syncthreads();
    #pragma unroll
    for (int i = 0; i < 4; ++i) {
        int r = row + i * 16;    // n within tile
        ushort4 o = { f2bf(tile[col4 * 4 + 0][r]), f2bf(tile[col4 * 4 + 1][r]),
                      f2bf(tile[col4 * 4 + 2][r]), f2bf(tile[col4 * 4 + 3][r]) };
        *(ushort4*)(Wt + (size_t)(bx * 64 + r) * K + by * 64 + col4 * 4) = o;
    }
}

// ---------------------------------------------------------------------------
// bf16 MFMA GEMM (m97 structure): C = relu(A @ Bt^T + bias).
// A [M,K] bf16 row-major, Bt [N,K] bf16 row-major, 128x128 tile, BK=32,
// 256 threads = 4 waves (2x2), each wave 64x64 via 4x4 mfma_f32_16x16x32_bf16.
// global_load_lds width=16: LDS dest is wave-uniform base + lane*16 -> LDS
// tiles are unpadded row-major 128x32 bf16 (lane order == memory order).
// OUT_BF16=1: store relu bf16 (feeds next GEMM); else fp32.
// ---------------------------------------------------------------------------
template <int OUT_BF16>
__global__ __launch_bounds__(256) void gemm_bf16_mfma(
    const unsigned short* __restrict__ A, const unsigned short* __restrict__ Bt,
    const float* __restrict__ bias, unsigned short* __restrict__ Cbf,
    float* __restrict__ Cf, int M, int N, int K)
{
    __shared__ unsigned short As[128 * 32];
    __shared__ unsigned short Bs[128 * 32];

    const int tid = threadIdx.x;
    const int wave = tid >> 6;
    const int lane = tid & 63;
    const int bn = blockIdx.x, bm = blockIdx.y;
    const int wm = (wave & 1) * 64;    // wave row offset in 128-tile
    const int wn = (wave >> 1) * 64;   // wave col offset

    const unsigned short* Ablk = A  + (size_t)(bm * 128) * K;
    const unsigned short* Bblk = Bt + (size_t)(bn * 128) * K;

    const int srow0 = wave * 32;        // this wave stages rows [srow0, srow0+32)
    const int lrow = lane >> 2;         // 0..15
    const int lcol = (lane & 3) * 8;    // bf16 element offset (16 B chunks)

    f32x4 acc[4][4] = {};

    for (int k0 = 0; k0 < K; k0 += 32) {
        #pragma unroll
        for (int j = 0; j < 2; ++j) {
            int r = srow0 + j * 16 + lrow;
            __builtin_amdgcn_global_load_lds(
                (const __attribute__((address_space(1))) void*)(Ablk + (size_t)r * K + k0 + lcol),
                (__attribute__((address_space(3))) void*)(As + (srow0 + j * 16) * 32),
                16, 0, 0);
            __builtin_amdgcn_global_load_lds(
                (const __attribute__((address_space(1))) void*)(Bblk + (size_t)r * K + k0 + lcol),
                (__attribute__((address_space(3))) void*)(Bs + (srow0 + j * 16) * 32),
                16, 0, 0);
        }
        __syncthreads();

        bf16x8 a[4], b[4];
        #pragma unroll
        for (int mt = 0; mt < 4; ++mt)
            a[mt] = *(const bf16x8*)(As + (wm + mt * 16 + (lane & 15)) * 32 + (lane >> 4) * 8);
        #pragma unroll
        for (int nt = 0; nt < 4; ++nt)
            b[nt] = *(const bf16x8*)(Bs + (wn + nt * 16 + (lane & 15)) * 32 + (lane >> 4) * 8);
        #pragma unroll
        for (int mt = 0; mt < 4; ++mt)
            #pragma unroll
            for (int nt = 0; nt < 4; ++nt)
                acc[mt][nt] = __builtin_amdgcn_mfma_f32_16x16x32_bf16(
                    a[mt], b[nt], acc[mt][nt], 0, 0, 0);
        __syncthreads();
    }

    // Epilogue. C/D frag: col = lane&15, row = (lane>>4)*4 + reg  [m89-verified]
    const int cm0 = bm * 128 + wm;
    const int cn0 = bn * 128 + wn;
    const int lc = lane & 15;
    const int lr = (lane >> 4) * 4;
    #pragma unroll
    for (int nt = 0; nt < 4; ++nt) {
        float bv = bias[cn0 + nt * 16 + lc];
        #pragma unroll
        for (int mt = 0; mt < 4; ++mt) {
            #pragma unroll
            for (int r = 0; r < 4; ++r) {
                float v = fmaxf(acc[mt][nt][r] + bv, 0.0f);
                size_t idx = (size_t)(cm0 + mt * 16 + lr + r) * N + cn0 + nt * 16 + lc;
                if (OUT_BF16) Cbf[idx] = f2bf(v);
                else          Cf[idx] = v;
            }
        }
    }
}

// ---------------------------------------------------------------------------
// Layer 3: scores[r] = dot(H[r,:], W3) + b3.  One wave per row, fp32.
// ---------------------------------------------------------------------------
__global__ __launch_bounds__(256) void matvec_bias(
    const float* __restrict__ H, const float* __restrict__ W,
    const float* __restrict__ b3, float* __restrict__ scores,
    float* __restrict__ out_scores, int N)
{
    const int wave = threadIdx.x >> 6;
    const int lane = threadIdx.x & 63;
    const int row  = blockIdx.x * 4 + wave;
    const float* h = H + (size_t)row * N;

    float s = 0.0f;
    for (int w = 0; w < N / 256; ++w) {
        float4 v = *(const float4*)(h + w * 256 + lane * 4);
        float4 g = *(const float4*)(W + w * 256 + lane * 4);
        s += v.x * g.x + v.y * g.y + v.z * g.z + v.w * g.w;
    }
    #pragma unroll
    for (int off = 32; off > 0; off >>= 1) s += __shfl_down(s, off);
    if (lane == 0) {
        float r = s + b3[0];
        scores[row] = r;
        out_scores[row] = r;
    }
}

// ---------------------------------------------------------------------------
// soft_rank over n=4096 scores, single block of 1024 threads.
// (unchanged from round 2 — bitonic sort + chunked PAV + merge + scatter)
// ---------------------------------------------------------------------------
__global__ __launch_bounds__(1024) void soft_rank_kernel(
    const float* __restrict__ scores, float* __restrict__ rank_out, int* nb_ws)
{
    constexpr int n = 4096;
    __shared__ __align__(16) unsigned char lds[65536];
    unsigned long long* keys = (unsigned long long*)lds;
    double* bsum  = (double*)lds;
    float*  svals = (float*)(lds + 32768);
    unsigned short* perm   = (unsigned short*)(lds + 49152);
    unsigned short* bstart = (unsigned short*)(lds + 57344);

    const int tid = threadIdx.x;

    for (int t = tid; t < n; t += 1024) {
        unsigned ub = __float_as_uint(scores[t]);
        unsigned m  = (ub & 0x80000000u) ? ~ub : (ub | 0x80000000u);
        unsigned d  = ~m;
        keys[t] = ((unsigned long long)d << 32) | (unsigned)t;
    }
    __syncthreads();

    for (int k = 2; k <= n; k <<= 1) {
        for (int j = k >> 1; j > 0; j >>= 1) {
            for (int t = tid; t < n; t += 1024) {
                int l = t ^ j;
                if (l > t) {
                    unsigned long long a = keys[t], b = keys[l];
                    bool up = ((t & k) == 0);
                    bool sw = up ? (a > b) : (a < b);
                    if (sw) { keys[t] = b; keys[l] = a; }
                }
            }
            __syncthreads();
        }
    }

    for (int t = tid; t < n; t += 1024) {
        unsigned long long key = keys[t];
        unsigned d = (unsigned)(key >> 32);
        unsigned m = ~d;
        unsigned ub = (m & 0x80000000u) ? (m ^ 0x80000000u) : ~m;
        svals[t] = __uint_as_float(ub);
        perm[t]  = (unsigned short)(key & 0xFFFFu);
    }
    __syncthreads();

    if (tid < 64) {
        const int base = tid << 6;
        int depth = 0;
        double rtsum = 0.0; int rtstart = 0;
        for (int s = 0; s < 64; ++s) {
            int i = base + s;
            double csum = (double)svals[i] - (double)(n - i);
            int cs = i;
            const int ce = i + 1;
            while (depth > 0) {
                if (rtsum * (double)(ce - cs) <= csum * (double)(cs - rtstart)) {
                    csum += rtsum; cs = rtstart; depth--;
                    if (depth > 0) {
                        rtsum = bsum[base + depth - 1];
                        rtstart = bstart[base + depth - 1];
                    }
                } else break;
            }
            if (depth > 0) {
                bsum[base + depth - 1] = rtsum;
                bstart[base + depth - 1] = (unsigned short)rtstart;
            }
            rtsum = csum; rtstart = cs; depth++;
        }
        bsum[base + depth - 1] = rtsum;
        bstart[base + depth - 1] = (unsigned short)rtstart;
        if (depth < 64) bstart[base + depth] = 0xFFFFu;
    }
    __syncthreads();

    if (tid == 0) {
        int g = 0;
        double gtsum = 0.0; int gtstart = 0;
        for (int c = 0; c < 64; ++c) {
            const int base = c << 6;
            for (int s = 0; s < 64; ++s) {
                const int r = base + s;
                int cs = bstart[r];
                if (cs == 0xFFFF) break;
                int ce;
                if (s < 63) {
                    int nx = bstart[r + 1];
                    ce = (nx == 0xFFFF) ? base + 64 : nx;
                } else ce = base + 64;
                double csum = bsum[r];
                while (g > 0) {
                    if (gtsum * (double)(ce - cs) <= csum * (double)(cs - gtstart)) {
                        csum += gtsum; cs = gtstart; g--;
                        if (g > 0) { gtsum = bsum[g - 1]; gtstart = bstart[g - 1]; }
                    } else break;
                }
                if (g > 0) {
                    bsum[g - 1] = gtsum;
                    bstart[g - 1] = (unsigned short)gtstart;
                }
                gtsum = csum; gtstart = cs; g++;
            }
        }
        bsum[g - 1] = gtsum;
        bstart[g - 1] = (unsigned short)gtstart;
        __hip_atomic_store(nb_ws, g, __ATOMIC_RELEASE, __HIP_MEMORY_SCOPE_AGENT);
    }
    __syncthreads();
    const int nb = __hip_atomic_load(nb_ws, __ATOMIC_ACQUIRE, __HIP_MEMORY_SCOPE_AGENT);

    for (int t = tid; t < n; t += 1024) {
        int lo = 0, hi = nb - 1;
        while (lo < hi) {
            int mid = (lo + hi + 1) >> 1;
            if ((int)bstart[mid] <= t) lo = mid; else hi = mid - 1;
        }
        int bs = bstart[lo];
        int be = (lo + 1 < nb) ? (int)bstart[lo + 1] : n;
        float mean = (float)(bsum[lo] / (double)(be - bs));
        rank_out[(int)perm[t]] = svals[t] - mean;
    }
}

// ---------------------------------------------------------------------------
extern "C" void kernel_launch(void* const* d_in, const int* in_sizes, int n_in,
                              void* d_out, int out_size, void* d_ws, size_t ws_size,
                              hipStream_t stream) {
    const float* x  = (const float*)d_in[0];
    const float* W1 = (const float*)d_in[1];
    const float* b1 = (const float*)d_in[2];
    const float* W2 = (const float*)d_in[3];
    const float* b2 = (const float*)d_in[4];
    const float* W3 = (const float*)d_in[5];
    const float* b3 = (const float*)d_in[6];
    float* out = (float*)d_out;   // [0,4096): rank, [4096,8192): scores

    const int B = 4096, D_IN = 512, H = 2048;

    // Workspace layout (bytes):
    char* ws = (char*)d_ws;
    unsigned short* h1  = (unsigned short*)(ws);                    // 16 MB bf16
    float*          h2  = (float*)(ws + (16u << 20));               // 32 MB fp32
    unsigned short* xb  = (unsigned short*)(ws + (48u << 20));      //  4 MB bf16
    unsigned short* W1t = (unsigned short*)(ws + (52u << 20));      //  2 MB bf16 [N,K]
    unsigned short* W2t = (unsigned short*)(ws + (54u << 20));      //  8 MB bf16 [N,K]
    float*          sc  = (float*)(ws + (62u << 20));               // 16 KB
    int*            nb  = (int*)(ws + (62u << 20) + 16384);

    // Prep: convert x; transpose+convert W1, W2.
    convert_bf16<<<(B * D_IN) / 1024, 256, 0, stream>>>(x, xb);
    transpose_convert<<<dim3(H / 64, D_IN / 64), 256, 0, stream>>>(W1, W1t, D_IN, H);
    transpose_convert<<<dim3(H / 64, H / 64), 256, 0, stream>>>(W2, W2t, H, H);

    // GEMM1: h1 = relu(x @ W1 + b1), bf16 out. M=4096 N=2048 K=512.
    gemm_bf16_mfma<1><<<dim3(H / 128, B / 128), 256, 0, stream>>>(
        xb, W1t, b1, h1, nullptr, B, H, D_IN);
    // GEMM2: h2 = relu(h1 @ W2 + b2), fp32 out. M=4096 N=2048 K=2048.
    gemm_bf16_mfma<0><<<dim3(H / 128, B / 128), 256, 0, stream>>>(
        h1, W2t, b2, nullptr, h2, B, H, H);

    matvec_bias<<<B / 4, 256, 0, stream>>>(h2, W3, b3, sc, out + B, H);
    soft_rank_kernel<<<1, 1024, 0, stream>>>(sc, out, nb);
}